// Round 5
// baseline (6329.590 us; speedup 1.0000x reference)
//
#include <hip/hip_runtime.h>

// ---------------------------------------------------------------------------
// CMAPFeatureExtractor: twin-branch GCN autoencoder on MI355X (gfx950).
// Round 5: LDS-bandwidth diagnosis -> B operand moved global->VGPR (weights
// are L2/L1-resident), LDS carries A only (64 KiB dbuf) -> 2 blocks/CU.
// LDS bytes/K-tile: 448KB -> 160KB; MFMA becomes the binding pipe.
// ---------------------------------------------------------------------------

typedef __attribute__((ext_vector_type(8))) short s16x8;   // 8 x bf16
typedef __attribute__((ext_vector_type(4))) short s16x4;   // 4 x bf16
typedef __attribute__((ext_vector_type(4))) float f32x4;

#define DEV static __device__ __forceinline__

DEV float b2f(ushort u) { return __builtin_bit_cast(float, (unsigned)u << 16); }
DEV ushort f2b(float f) {
  unsigned x = __builtin_bit_cast(unsigned, f);
  unsigned r = x + 0x7fffu + ((x >> 16) & 1u);   // RNE; inputs are finite
  return (ushort)(r >> 16);
}

typedef const __attribute__((address_space(1))) void* gas_ptr;
typedef __attribute__((address_space(3))) void* las_ptr;

// ---------------------------------------------------------------------------
// 256^2 GEMM, A via LDS (dbuf 2x32KB, swizzled), B via global->reg (dbuf in
// VGPRs, static ping-pong). C[M,N] = act(A[M,K] @ BT[N,K]^T + bias).
// M%256==0, N%256==0, K%64==0. 8 waves, wave-tile 128x64.
// ---------------------------------------------------------------------------
template<int ACT>   // 0 = relu, 1 = silu
__global__ __launch_bounds__(512, 2) void gemm256g(
    const ushort* __restrict__ A, const ushort* __restrict__ BT,
    const float* __restrict__ bias, ushort* __restrict__ C,
    int M, int N, int K)
{
  __shared__ __align__(16) ushort Asb[2 * 256 * 64];   // 64 KiB
  char* Lb = (char*)Asb;

  const int tid = threadIdx.x, lane = tid & 63, w = tid >> 6;
  const int wm = w >> 2, wn = w & 3;       // 2M x 4N wave grid

  // T1: XCD-aware bijective swizzle (nwg % 8 == 0 for every call below)
  const int gx  = gridDim.x;
  const int nwg = gx * gridDim.y;
  const int wid = blockIdx.y * gx + blockIdx.x;
  const int q   = nwg >> 3;
  const int Lw  = (wid & 7) * q + (wid >> 3);
  const int bn  = Lw % gx;
  const int bm  = Lw / gx;

  const ushort* Abase = A + (size_t)bm * 256 * K;
  const int T = K >> 6;                    // K-tiles of 64, T >= 1

  // ---- A staging: linear LDS dest, inverse-swizzled global source.
  // thread covers rows j*64 + (tid>>3); read-side XOR: byte ^= (r&7)<<4.
  const int sr8  = tid >> 3;                         // w*8 + (lane>>3)
  const int scol = (((tid & 7) ^ (sr8 & 7)) << 3);   // elements

#define STAGEA(buf, kt)                                                      \
  { const int _k0 = (kt) * 64;                                               \
    _Pragma("unroll") for (int j = 0; j < 4; ++j) {                          \
      __builtin_amdgcn_global_load_lds(                                      \
        (gas_ptr)(Abase + (size_t)(j * 64 + sr8) * K + _k0 + scol),          \
        (las_ptr)(Lb + (buf) * 32768 + (j * 64 + w * 8) * 128), 16, 0, 0);   \
    } }

  // ---- B: global->reg, 8 x dwordx4 per tile (each instr: 16 full 64B lines)
  const int lr = lane & 15, lk = lane >> 4;
  const ushort* Brow0 = BT + (size_t)(bn * 256 + wn * 64 + lr) * K + lk * 8;

#define LOADB(dst, kt)                                                       \
  { _Pragma("unroll") for (int p = 0; p < 4; ++p)                            \
      _Pragma("unroll") for (int kk = 0; kk < 2; ++kk)                       \
        dst[p * 2 + kk] = *(const s16x8*)(Brow0 + (size_t)p * 16 * K         \
                                          + (kt) * 64 + kk * 32);            \
  }

  // ---- A-frag read offsets: r = wm*128 + f*16 + lr; byte = r*128 +
  //      ((kk<<6 | lk<<4) ^ ((lr&7)<<4))   (round-2-verified: 0 conflicts)
  const int sw = (lr & 7) << 4;
  int offA[8];
  #pragma unroll
  for (int f = 0; f < 8; ++f)
    offA[f] = (wm * 128 + f * 16 + lr) * 128;

  f32x4 acc[8][4];
  #pragma unroll
  for (int f = 0; f < 8; ++f)
    #pragma unroll
    for (int p = 0; p < 4; ++p) acc[f][p] = f32x4{0.f, 0.f, 0.f, 0.f};

  s16x8 bfA[8], bfB[8];

  // tile body: prefetch t+1 (A->LDS nbuf, B->regs bfN), compute tile t.
  // __syncthreads drains vmcnt(0)+lgkmcnt(0): prefetch landed, reads done.
#define TILE(t, cbuf, bfC, bfN, nbuf)                                        \
  { if ((t) + 1 < T) { STAGEA(nbuf, (t) + 1); LOADB(bfN, (t) + 1); }         \
    _Pragma("unroll") for (int kk = 0; kk < 2; ++kk) {                       \
      s16x8 af[8];                                                           \
      _Pragma("unroll") for (int f = 0; f < 8; ++f)                          \
        af[f] = *(const s16x8*)(Lb + (cbuf) * 32768 + offA[f]                \
                                + (((kk << 6) | (lk << 4)) ^ sw));           \
      __builtin_amdgcn_s_setprio(1);                                         \
      _Pragma("unroll") for (int f = 0; f < 8; ++f)                          \
        _Pragma("unroll") for (int p = 0; p < 4; ++p)                        \
          acc[f][p] = __builtin_amdgcn_mfma_f32_16x16x32_bf16(               \
              af[f], bfC[p * 2 + kk], acc[f][p], 0, 0, 0);                   \
      __builtin_amdgcn_s_setprio(0);                                         \
    }                                                                        \
    __syncthreads(); }

  // prologue
  LOADB(bfA, 0);
  STAGEA(0, 0);
  __syncthreads();

  int t = 0;
  for (;;) {
    TILE(t, 0, bfA, bfB, 1);
    if (++t == T) break;
    TILE(t, 1, bfB, bfA, 0);
    if (++t == T) break;
  }

  // epilogue: C/D frag layout col=lane&15, row=(lane>>4)*4+reg
  const int row0 = bm * 256 + wm * 128;
  const int col0 = bn * 256 + wn * 64;
  #pragma unroll
  for (int f = 0; f < 8; ++f) {
    const int row = row0 + f * 16 + lk * 4;
    #pragma unroll
    for (int p = 0; p < 4; ++p) {
      const int col = col0 + p * 16 + lr;
      const float bv = bias[col];
      #pragma unroll
      for (int r = 0; r < 4; ++r) {
        float v = acc[f][p][r] + bv;
        if (ACT == 0) v = fmaxf(v, 0.f);
        else          v = v / (1.f + __expf(-v));
        C[(size_t)(row + r) * N + col] = f2b(v);
      }
    }
  }
#undef TILE
#undef LOADB
#undef STAGEA
}

// ---------------------------------------------------------------------------
// small 128^2 GEMM (te-table only: M=128).
// ---------------------------------------------------------------------------
template<int ACT>
__global__ __launch_bounds__(256) void gemm_bt(
    const ushort* __restrict__ A, const ushort* __restrict__ BT,
    const float* __restrict__ bias, ushort* __restrict__ C,
    int M, int N, int K)
{
  __shared__ ushort As[128 * 64];
  __shared__ ushort Bs[128 * 64];

  const int tid  = threadIdx.x;
  const int lane = tid & 63;
  const int w    = tid >> 6;

  const int gx  = gridDim.x;
  const int nwg = gx * gridDim.y;
  const int wid = blockIdx.y * gx + blockIdx.x;
  const int q   = nwg >> 3;
  const int L   = (wid & 7) * q + (wid >> 3);
  const int bn  = L % gx;
  const int bm  = L / gx;

  const int wm = w >> 1, wn = w & 1;
  const int lr = lane & 15;
  const int lk = lane >> 4;

  const ushort* Abase = A  + (size_t)bm * 128 * K;
  const ushort* Bbase = BT + (size_t)bn * 128 * K;
  const int srow = w * 8 + (lane >> 3);
  const int scol = (lane & 7) * 8;

  f32x4 acc[4][4];
  #pragma unroll
  for (int i = 0; i < 4; i++)
    #pragma unroll
    for (int j = 0; j < 4; j++) acc[i][j] = f32x4{0.f, 0.f, 0.f, 0.f};

  for (int k0 = 0; k0 < K; k0 += 64) {
    #pragma unroll
    for (int i = 0; i < 4; i++) {
      const int r = srow + i * 32;
      __builtin_amdgcn_global_load_lds(
          (gas_ptr)(Abase + (size_t)r * K + k0 + scol),
          (las_ptr)(As + w * 512 + i * 2048), 16, 0, 0);
    }
    #pragma unroll
    for (int i = 0; i < 4; i++) {
      const int r = srow + i * 32;
      __builtin_amdgcn_global_load_lds(
          (gas_ptr)(Bbase + (size_t)r * K + k0 + scol),
          (las_ptr)(Bs + w * 512 + i * 2048), 16, 0, 0);
    }
    __syncthreads();

    #pragma unroll
    for (int kc = 0; kc < 64; kc += 32) {
      s16x8 af[4], bf[4];
      #pragma unroll
      for (int mi = 0; mi < 4; mi++)
        af[mi] = *(const s16x8*)&As[(wm * 64 + mi * 16 + lr) * 64 + kc + lk * 8];
      #pragma unroll
      for (int ni = 0; ni < 4; ni++)
        bf[ni] = *(const s16x8*)&Bs[(wn * 64 + ni * 16 + lr) * 64 + kc + lk * 8];
      #pragma unroll
      for (int mi = 0; mi < 4; mi++)
        #pragma unroll
        for (int ni = 0; ni < 4; ni++)
          acc[mi][ni] = __builtin_amdgcn_mfma_f32_16x16x32_bf16(
              af[mi], bf[ni], acc[mi][ni], 0, 0, 0);
    }
    __syncthreads();
  }

  const int row0 = bm * 128 + wm * 64;
  const int col0 = bn * 128 + wn * 64;
  #pragma unroll
  for (int ni = 0; ni < 4; ni++) {
    const int col = col0 + ni * 16 + lr;
    const float bv = bias[col];
    #pragma unroll
    for (int mi = 0; mi < 4; mi++) {
      const int row = row0 + mi * 16 + lk * 4;
      #pragma unroll
      for (int r = 0; r < 4; r++) {
        float v = acc[mi][ni][r] + bv;
        if (ACT == 0) v = fmaxf(v, 0.f);
        else          v = v / (1.f + __expf(-v));
        C[(size_t)(row + r) * N + col] = f2b(v);
      }
    }
  }
}

// ---------------------------------------------------------------------------
// weight transpose+convert: W[K,N] f32 -> WT[N,Kpad] bf16 (zero-pad k>=K)
// ---------------------------------------------------------------------------
__global__ void trans_conv(const float* __restrict__ W, ushort* __restrict__ WT,
                           int K, int N, int Kpad)
{
  __shared__ float tile[32][33];
  const int n0 = blockIdx.x * 32, k0 = blockIdx.y * 32;
  const int tx = threadIdx.x, ty = threadIdx.y;   // (32,8)
  #pragma unroll
  for (int r = 0; r < 4; r++) {
    const int k = k0 + ty + r * 8;
    tile[ty + r * 8][tx] = (k < K) ? W[(size_t)k * N + n0 + tx] : 0.f;
  }
  __syncthreads();
  #pragma unroll
  for (int r = 0; r < 4; r++) {
    const int n = n0 + ty + r * 8;
    WT[(size_t)n * Kpad + k0 + tx] = f2b(tile[tx][ty + r * 8]);
  }
}

// f32 [R,Cin] -> bf16 [R,Cpad], zero-padded columns
__global__ void conv_pad(const float* __restrict__ in, ushort* __restrict__ out,
                         int R, int Cin, int Cpad)
{
  const int gid = blockIdx.x * 256 + threadIdx.x;
  if (gid >= R * Cpad) return;
  const int r = gid / Cpad, c = gid - r * Cpad;
  out[gid] = (c < Cin) ? f2b(in[(size_t)r * Cin + c]) : (ushort)0;
}

// ---------------------------------------------------------------------------
// LayerNorm over 1024 cols (eps=1e-3), bf16 in/out. One block (256 thr) / row.
// ---------------------------------------------------------------------------
DEV void ln_row(const ushort* __restrict__ in, const float* __restrict__ gamma,
                const float* __restrict__ beta, ushort* __restrict__ outp,
                int tid, float* red)
{
  s16x4 v = *(const s16x4*)&in[tid * 4];
  const float x0 = b2f((ushort)v[0]), x1 = b2f((ushort)v[1]);
  const float x2 = b2f((ushort)v[2]), x3 = b2f((ushort)v[3]);
  float s = x0 + x1 + x2 + x3;
  float qq = x0 * x0 + x1 * x1 + x2 * x2 + x3 * x3;
  #pragma unroll
  for (int o = 32; o > 0; o >>= 1) { s += __shfl_down(s, o); qq += __shfl_down(qq, o); }
  const int wv = tid >> 6, lane = tid & 63;
  __syncthreads();
  if (lane == 0) { red[wv] = s; red[4 + wv] = qq; }
  __syncthreads();
  s  = red[0] + red[1] + red[2] + red[3];
  qq = red[4] + red[5] + red[6] + red[7];
  const float m   = s * (1.f / 1024.f);
  const float var = qq * (1.f / 1024.f) - m * m;
  const float rs  = rsqrtf(var + 1e-3f);
  const int c = tid * 4;
  s16x4 o;
  o[0] = (short)f2b(gamma[c + 0] * ((x0 - m) * rs) + beta[c + 0]);
  o[1] = (short)f2b(gamma[c + 1] * ((x1 - m) * rs) + beta[c + 1]);
  o[2] = (short)f2b(gamma[c + 2] * ((x2 - m) * rs) + beta[c + 2]);
  o[3] = (short)f2b(gamma[c + 3] * ((x3 - m) * rs) + beta[c + 3]);
  *(s16x4*)&outp[c] = o;
}

__global__ void ln_te(const ushort* __restrict__ in, const float* __restrict__ g,
                      const float* __restrict__ b, ushort* __restrict__ out)
{
  __shared__ float red[8];
  ln_row(in + (size_t)blockIdx.x * 1024, g, b,
         out + (size_t)blockIdx.x * 1024, threadIdx.x, red);
}

// gather te row + LN(ge) + LN(ce) -> X[b,3,1024]
__global__ void assembleX(const int* __restrict__ t, const ushort* __restrict__ tetab,
                          const ushort* __restrict__ ge, const ushort* __restrict__ ce,
                          const float* __restrict__ gG, const float* __restrict__ gB,
                          const float* __restrict__ cG, const float* __restrict__ cB,
                          ushort* __restrict__ X)
{
  __shared__ float red[8];
  const int b = blockIdx.x, tid = threadIdx.x;
  const int tt = t[b];
  *(s16x4*)&X[(size_t)b * 3072 + tid * 4] =
      *(const s16x4*)&tetab[(size_t)tt * 1024 + tid * 4];
  ln_row(ge + (size_t)b * 1024, gG, gB, X + (size_t)b * 3072 + 1024, tid, red);
  ln_row(ce + (size_t)b * 1024, cG, cB, X + (size_t)b * 3072 + 2048, tid, red);
}

// ---------------------------------------------------------------------------
// per-sample 3x3 adjacency mix: out[b,i,:] = sum_j A[b,i,j] * x[b,j,:]
// ---------------------------------------------------------------------------
__global__ void mix3(const ushort* __restrict__ x, const float* __restrict__ Am,
                     ushort* __restrict__ out, int d, int lg, int nB)
{
  const int gid = blockIdx.x * 256 + threadIdx.x;
  const int b = gid >> lg;
  if (b >= nB) return;
  const int c8 = (gid & ((1 << lg) - 1)) << 3;
  const ushort* xb = x   + (size_t)b * 3 * d + c8;
  ushort*       ob = out + (size_t)b * 3 * d + c8;
  s16x8 x0 = *(const s16x8*)xb;
  s16x8 x1 = *(const s16x8*)(xb + d);
  s16x8 x2 = *(const s16x8*)(xb + 2 * d);
  float f0[8], f1[8], f2[8];
  #pragma unroll
  for (int e = 0; e < 8; e++) {
    f0[e] = b2f((ushort)x0[e]); f1[e] = b2f((ushort)x1[e]); f2[e] = b2f((ushort)x2[e]);
  }
  const float* Ab = Am + (size_t)b * 9;
  #pragma unroll
  for (int j = 0; j < 3; j++) {
    const float a0 = Ab[j * 3], a1 = Ab[j * 3 + 1], a2 = Ab[j * 3 + 2];
    s16x8 o;
    #pragma unroll
    for (int e = 0; e < 8; e++)
      o[e] = (short)f2b(a0 * f0[e] + a1 * f1[e] + a2 * f2[e]);
    *(s16x8*)(ob + j * d) = o;
  }
}

// ---------------------------------------------------------------------------
// losses (standalone)
// ---------------------------------------------------------------------------
__global__ void zloss_k(const ushort* __restrict__ z1, const ushort* __restrict__ z2,
                        float* __restrict__ out, int n8)
{
  const int gid = blockIdx.x * 256 + threadIdx.x;
  if (gid >= n8) return;
  const size_t i = (size_t)gid * 8;
  s16x8 a = *(const s16x8*)&z1[i];
  s16x8 b = *(const s16x8*)&z2[i];
  f32x4 o0, o1;
  #pragma unroll
  for (int e = 0; e < 4; e++) {
    float d0 = b2f((ushort)a[e]) - b2f((ushort)b[e]);
    float d1 = b2f((ushort)a[e + 4]) - b2f((ushort)b[e + 4]);
    o0[e] = d0 * d0; o1[e] = d1 * d1;
  }
  *(f32x4*)&out[i] = o0; *(f32x4*)&out[i + 4] = o1;
}

template<int ADD>
__global__ void xloss_k(const ushort* __restrict__ X, const ushort* __restrict__ Xh,
                        float* __restrict__ out, int n8)
{
  const int gid = blockIdx.x * 256 + threadIdx.x;
  if (gid >= n8) return;
  const size_t i = (size_t)gid * 8;
  s16x8 a = *(const s16x8*)&X[i];
  s16x8 b = *(const s16x8*)&Xh[i];
  f32x4 o0, o1;
  #pragma unroll
  for (int e = 0; e < 4; e++) {
    float d0 = b2f((ushort)a[e]) - b2f((ushort)b[e]);
    float d1 = b2f((ushort)a[e + 4]) - b2f((ushort)b[e + 4]);
    o0[e] = 0.5f * d0 * d0; o1[e] = 0.5f * d1 * d1;
  }
  if (ADD) {
    f32x4 p0 = *(const f32x4*)&out[i];
    f32x4 p1 = *(const f32x4*)&out[i + 4];
    #pragma unroll
    for (int e = 0; e < 4; e++) { o0[e] += p0[e]; o1[e] += p1[e]; }
  }
  *(f32x4*)&out[i] = o0; *(f32x4*)&out[i + 4] = o1;
}

// ---------------------------------------------------------------------------
extern "C" void kernel_launch(void* const* d_in, const int* in_sizes, int n_in,
                              void* d_out, int out_size, void* d_ws, size_t ws_size,
                              hipStream_t stream)
{
  const int B = 16384, S = 3 * B;
  const int*   t1 = (const int*)d_in[0];
  const float* g1 = (const float*)d_in[1];
  const float* c1 = (const float*)d_in[2];
  const float* A1 = (const float*)d_in[3];
  const int*   t2 = (const int*)d_in[4];
  const float* g2 = (const float*)d_in[5];
  const float* c2 = (const float*)d_in[6];
  const float* A2 = (const float*)d_in[7];
  const float* embed = (const float*)d_in[8];
  const float* Wt = (const float*)d_in[9];  const float* bt = (const float*)d_in[10];
  const float* Wg = (const float*)d_in[11]; const float* bg = (const float*)d_in[12];
  const float* Wc = (const float*)d_in[13]; const float* bc = (const float*)d_in[14];
  const float* lntg = (const float*)d_in[15]; const float* lntb = (const float*)d_in[16];
  const float* lngg = (const float*)d_in[17]; const float* lngb = (const float*)d_in[18];
  const float* lncg = (const float*)d_in[19]; const float* lncb = (const float*)d_in[20];
  const float* eW0 = (const float*)d_in[21]; const float* eb0 = (const float*)d_in[22];
  const float* eW1 = (const float*)d_in[23]; const float* eb1 = (const float*)d_in[24];
  const float* eW2 = (const float*)d_in[25]; const float* eb2 = (const float*)d_in[26];
  const float* dW0 = (const float*)d_in[27]; const float* db0 = (const float*)d_in[28];
  const float* dW1 = (const float*)d_in[29]; const float* db1 = (const float*)d_in[30];
  const float* dW2 = (const float*)d_in[31]; const float* db2 = (const float*)d_in[32];
  float* out = (float*)d_out;
  (void)in_sizes; (void)n_in; (void)out_size; (void)ws_size;

  char* ws = (char*)d_ws; size_t off = 0;
  auto alloc = [&](size_t bytes) -> void* {
    void* p = ws + off; off += (bytes + 255) & ~(size_t)255; return p;
  };
  ushort* WtT  = (ushort*)alloc((size_t)1024 * 1024 * 2);
  ushort* WgT  = (ushort*)alloc((size_t)1024 * 896 * 2);
  ushort* WcT  = (ushort*)alloc((size_t)1024 * 128 * 2);
  ushort* E0T  = (ushort*)alloc((size_t)1024 * 1024 * 2);
  ushort* E1T  = (ushort*)alloc((size_t)512 * 1024 * 2);
  ushort* E2T  = (ushort*)alloc((size_t)256 * 512 * 2);
  ushort* D0T  = (ushort*)alloc((size_t)512 * 256 * 2);
  ushort* D1T  = (ushort*)alloc((size_t)1024 * 512 * 2);
  ushort* D2T  = (ushort*)alloc((size_t)1024 * 1024 * 2);
  ushort* embB = (ushort*)alloc((size_t)128 * 1024 * 2);
  ushort* teraw= (ushort*)alloc((size_t)128 * 1024 * 2);
  ushort* tetab= (ushort*)alloc((size_t)128 * 1024 * 2);
  ushort* gB[2] = {(ushort*)alloc((size_t)B * 896 * 2), (ushort*)alloc((size_t)B * 896 * 2)};
  ushort* cB[2] = {(ushort*)alloc((size_t)B * 128 * 2), (ushort*)alloc((size_t)B * 128 * 2)};
  ushort* zB[2] = {(ushort*)alloc((size_t)S * 256 * 2), (ushort*)alloc((size_t)S * 256 * 2)};
  ushort* Xb = (ushort*)alloc((size_t)S * 1024 * 2);
  ushort* b0 = (ushort*)alloc((size_t)S * 1024 * 2);
  ushort* b1 = (ushort*)alloc((size_t)S * 1024 * 2);

  const dim3 TB(32, 8);
  // weights -> bf16 transposed [N][Kpad]
  trans_conv<<<dim3(32, 32), TB, 0, stream>>>(Wt,  WtT, 1024, 1024, 1024);
  trans_conv<<<dim3(32, 28), TB, 0, stream>>>(Wg,  WgT,  772, 1024,  896);
  trans_conv<<<dim3(32,  4), TB, 0, stream>>>(Wc,  WcT,  100, 1024,  128);
  trans_conv<<<dim3(32, 32), TB, 0, stream>>>(eW0, E0T, 1024, 1024, 1024);
  trans_conv<<<dim3(16, 32), TB, 0, stream>>>(eW1, E1T, 1024,  512, 1024);
  trans_conv<<<dim3( 8, 16), TB, 0, stream>>>(eW2, E2T,  512,  256,  512);
  trans_conv<<<dim3(16,  8), TB, 0, stream>>>(dW0, D0T,  256,  512,  256);
  trans_conv<<<dim3(32, 16), TB, 0, stream>>>(dW1, D1T,  512, 1024,  512);
  trans_conv<<<dim3(32, 32), TB, 0, stream>>>(dW2, D2T, 1024, 1024, 1024);
  // activations -> bf16 (K zero-padded)
  conv_pad<<<512, 256, 0, stream>>>(embed, embB, 128, 1024, 1024);
  conv_pad<<<(B * 896 + 255) / 256, 256, 0, stream>>>(g1, gB[0], B, 772, 896);
  conv_pad<<<(B * 896 + 255) / 256, 256, 0, stream>>>(g2, gB[1], B, 772, 896);
  conv_pad<<<B * 128 / 256, 256, 0, stream>>>(c1, cB[0], B, 100, 128);
  conv_pad<<<B * 128 / 256, 256, 0, stream>>>(c2, cB[1], B, 100, 128);
  // te table: relu(embed@Wt+bt) then LN  (128 tokens only)
  gemm_bt<0><<<dim3(8, 1), 256, 0, stream>>>(embB, WtT, bt, teraw, 128, 1024, 1024);
  ln_te<<<128, 256, 0, stream>>>(teraw, lntg, lntb, tetab);

  const size_t ZLEN = (size_t)S * 256;
  for (int br = 0; br < 2; ++br) {
    const int*   t    = br ? t2 : t1;
    const float* Aadj = br ? A2 : A1;
    // input projections (gemm256g: M%256, N%256, K%64 all satisfied)
    gemm256g<0><<<dim3(4, B / 256), 512, 0, stream>>>(gB[br], WgT, bg, b0, B, 1024, 896);
    gemm256g<0><<<dim3(4, B / 256), 512, 0, stream>>>(cB[br], WcT, bc, b1, B, 1024, 128);
    assembleX<<<B, 256, 0, stream>>>(t, tetab, b0, b1, lngg, lngb, lncg, lncb, Xb);
    // encoder (relu)
    mix3<<<(B << 7) / 256, 256, 0, stream>>>(Xb, Aadj, b0, 1024, 7, B);
    gemm256g<0><<<dim3(4, S / 256), 512, 0, stream>>>(b0, E0T, eb0, b1, S, 1024, 1024);
    mix3<<<(B << 7) / 256, 256, 0, stream>>>(b1, Aadj, b0, 1024, 7, B);
    gemm256g<0><<<dim3(2, S / 256), 512, 0, stream>>>(b0, E1T, eb1, b1, S, 512, 1024);
    mix3<<<(B << 6) / 256, 256, 0, stream>>>(b1, Aadj, b0, 512, 6, B);
    gemm256g<0><<<dim3(1, S / 256), 512, 0, stream>>>(b0, E2T, eb2, zB[br], S, 256, 512);
    // decoder (silu)
    mix3<<<(B << 5) / 256, 256, 0, stream>>>(zB[br], Aadj, b0, 256, 5, B);
    gemm256g<1><<<dim3(2, S / 256), 512, 0, stream>>>(b0, D0T, db0, b1, S, 512, 256);
    mix3<<<(B << 6) / 256, 256, 0, stream>>>(b1, Aadj, b0, 512, 6, B);
    gemm256g<1><<<dim3(4, S / 256), 512, 0, stream>>>(b0, D1T, db1, b1, S, 1024, 512);
    mix3<<<(B << 7) / 256, 256, 0, stream>>>(b1, Aadj, b0, 1024, 7, B);
    gemm256g<1><<<dim3(4, S / 256), 512, 0, stream>>>(b0, D2T, db2, b1, S, 1024, 1024);
    // X reconstruction loss (br0 writes, br1 accumulates)
    if (br == 0)
      xloss_k<0><<<S * 1024 / 8 / 256, 256, 0, stream>>>(Xb, b1, out + ZLEN, S * 1024 / 8);
    else
      xloss_k<1><<<S * 1024 / 8 / 256, 256, 0, stream>>>(Xb, b1, out + ZLEN, S * 1024 / 8);
  }
  zloss_k<<<S * 256 / 8 / 256, 256, 0, stream>>>(zB[0], zB[1], out, S * 256 / 8);
}

// Round 7
// 1572.204 us; speedup vs baseline: 4.0259x; 4.0259x over previous
//
#include <hip/hip_runtime.h>

// ---------------------------------------------------------------------------
// CMAPFeatureExtractor: twin-branch GCN autoencoder on MI355X (gfx950).
// Round 7: round-6 fragment-reuse schedule with the macro-capture bug fixed
// (READ_A/READ_B declared an internal 'cb' shadowing the buffer index passed
// as macro arg 'cb' -> LDS reads at ~3MB offsets -> garbage). All macro
// internals now underscore-prefixed. Schedule unchanged: per tile 4 phases
// (0,0)(0,1)(1,1)(1,0), reads 12/4/8/4, stage 1 half/phase, vmcnt(6) at P4.
// ---------------------------------------------------------------------------

typedef __attribute__((ext_vector_type(8))) short s16x8;   // 8 x bf16
typedef __attribute__((ext_vector_type(4))) short s16x4;   // 4 x bf16
typedef __attribute__((ext_vector_type(4))) float f32x4;

#define DEV static __device__ __forceinline__

DEV float b2f(ushort u) { return __builtin_bit_cast(float, (unsigned)u << 16); }
DEV ushort f2b(float f) {
  unsigned x = __builtin_bit_cast(unsigned, f);
  unsigned r = x + 0x7fffu + ((x >> 16) & 1u);   // RNE; inputs are finite
  return (ushort)(r >> 16);
}

typedef const __attribute__((address_space(1))) void* gas_ptr;
typedef __attribute__((address_space(3))) void* las_ptr;

// ---------------------------------------------------------------------------
// 256^2 GEMM, 4-phase fragment-reuse schedule (m201-derived).
// C[M,N] = act(A[M,K] @ BT[N,K]^T + bias), bf16 in/out, f32 acc.
// M%256==0, N%256==0, K%128==0 (T even, >=2). 8 waves, wave-tile 128x64.
// LDS 128 KiB: buf c in {0,1}: A at (c*2+0)*32KB, B at (c*2+1)*32KB.
// ---------------------------------------------------------------------------
template<int ACT>   // 0 = relu, 1 = silu
__global__ __launch_bounds__(512, 2) void gemm256(
    const ushort* __restrict__ A, const ushort* __restrict__ BT,
    const float* __restrict__ bias, ushort* __restrict__ C,
    int M, int N, int K)
{
  __shared__ __align__(16) ushort ldsbuf[65536];   // 128 KiB
  char* Lb = (char*)ldsbuf;

  const int tid = threadIdx.x, lane = tid & 63, w = tid >> 6;
  const int wm = w >> 2, wn = w & 3;              // 2M x 4N wave grid

  // T1: XCD-aware bijective swizzle (nwg % 8 == 0 for every call below)
  const int gx  = gridDim.x;
  const int nwg = gx * gridDim.y;
  const int wid = blockIdx.y * gx + blockIdx.x;
  const int q   = nwg >> 3;
  const int Lw  = (wid & 7) * q + (wid >> 3);
  const int bn  = Lw % gx;
  const int bm  = Lw / gx;

  const ushort* Abase = A  + (size_t)bm * 256 * K;
  const ushort* Bbase = BT + (size_t)bn * 256 * K;
  const int T = K >> 6;                            // even, >= 2

  // staging: linear LDS dest, inverse-swizzled global source (rule #21)
  const int srow = w * 8 + (lane >> 3);                      // + half*128 + j*64
  const int scol = (((lane & 7) ^ (lane >> 3)) << 3);        // ushorts

  // buf in {0,1}; m: 0=A,1=B; half in {0,1}; k0 in elements
#define STAGE(buf, m, half, Gb, k0)                                          \
  {                                                                          \
    _Pragma("unroll") for (int _j = 0; _j < 2; ++_j) {                       \
      const ushort* _src = (Gb) + (size_t)((half)*128 + _j*64 + srow) * K    \
                           + (k0) + scol;                                    \
      ushort* _dst = (ushort*)(Lb + ((buf)*2 + (m)) * 32768                  \
                               + ((half)*128 + _j*64 + w*8) * 128);          \
      __builtin_amdgcn_global_load_lds((gas_ptr)_src, (las_ptr)_dst, 16,0,0);\
    }                                                                        \
  }

  const int lr = lane & 15, lk = lane >> 4;

  // fragment reads (T2 swizzle, verified round 2: 0 bank conflicts).
  // NOTE: all internals underscore-prefixed — round-6 bug was the internal
  // 'cb' capturing the buffer-index argument also named 'cb'.
#define READ_A(dst, c, mh)                                                   \
  _Pragma("unroll") for (int _i = 0; _i < 4; ++_i)                           \
    _Pragma("unroll") for (int _kk = 0; _kk < 2; ++_kk) {                    \
      const int _r   = (mh)*128 + wm*64 + _i*16 + lr;                        \
      const int _cbb = _kk*64 + lk*16;                                       \
      dst[_i][_kk] = *(const s16x8*)(Lb + ((c)*2 + 0)*32768 + _r*128         \
                                     + (_cbb ^ ((_r & 7) << 4)));            \
    }
#define READ_B(dst, c, nh)                                                   \
  _Pragma("unroll") for (int _p = 0; _p < 2; ++_p)                           \
    _Pragma("unroll") for (int _kk = 0; _kk < 2; ++_kk) {                    \
      const int _r   = (nh)*128 + wn*32 + _p*16 + lr;                        \
      const int _cbb = _kk*64 + lk*16;                                       \
      dst[_p][_kk] = *(const s16x8*)(Lb + ((c)*2 + 1)*32768 + _r*128         \
                                     + (_cbb ^ ((_r & 7) << 4)));            \
    }

#define MFMA_Q(mh, nh)                                                       \
  _Pragma("unroll") for (int _i = 0; _i < 4; ++_i)                           \
    _Pragma("unroll") for (int _p = 0; _p < 2; ++_p)                         \
      _Pragma("unroll") for (int _kk = 0; _kk < 2; ++_kk)                    \
        acc[(mh)*4 + _i][(nh)*2 + _p] =                                      \
            __builtin_amdgcn_mfma_f32_16x16x32_bf16(                         \
                af[_i][_kk], bf[_p][_kk], acc[(mh)*4 + _i][(nh)*2 + _p],     \
                0, 0, 0);

#define MIDBAR  do { __builtin_amdgcn_s_barrier();                           \
                     asm volatile("s_waitcnt lgkmcnt(0)" ::: "memory");      \
                     __builtin_amdgcn_sched_barrier(0);                      \
                     __builtin_amdgcn_s_setprio(1); } while (0)
#define ENDBAR  do { __builtin_amdgcn_s_setprio(0);                          \
                     __builtin_amdgcn_s_barrier(); } while (0)

  f32x4 acc[8][4];
  #pragma unroll
  for (int i = 0; i < 8; ++i)
    #pragma unroll
    for (int j = 0; j < 4; ++j) acc[i][j] = f32x4{0.f, 0.f, 0.f, 0.f};

  // --- prologue: tile0 (A0,B0,B1,A1) + tile1 (A0,B1,A1); vmcnt(6) -> tile0
  //     landed, 3 halves of tile1 in flight (steady-state pattern).
  STAGE(0, 0, 0, Abase, 0);
  STAGE(0, 1, 0, Bbase, 0);
  STAGE(0, 1, 1, Bbase, 0);
  STAGE(0, 0, 1, Abase, 0);
  STAGE(1, 0, 0, Abase, 64);
  STAGE(1, 1, 1, Bbase, 64);
  STAGE(1, 0, 1, Abase, 64);
  asm volatile("s_waitcnt vmcnt(6)" ::: "memory");
  __builtin_amdgcn_s_barrier();

  // --- main loop: per tile 4 phases, quadrants (0,0)(0,1)(1,1)(1,0).
  // Stage plan (WAR gap >= 1 barrier; RAW closed by vmcnt(6) at P4):
  //   P1: B0(t+1) -> buf nb;  P2: A0(t+2) -> buf cb;
  //   P3: B1(t+2) -> buf cb;  P4: A1(t+2) -> buf cb.
  for (int t = 0; t < T; ++t) {
    const int cbuf = t & 1, nbuf = cbuf ^ 1;
    const int k1 = ((t + 1 < T) ? t + 1 : t + 1 - T) * 64;
    const int k2 = ((t + 2 < T) ? t + 2 : t + 2 - T) * 64;
    s16x8 af[4][2], bf[2][2];
    // P1: q(0,0) — 12 reads
    READ_A(af, cbuf, 0);
    READ_B(bf, cbuf, 0);
    STAGE(nbuf, 1, 0, Bbase, k1);
    asm volatile("s_waitcnt lgkmcnt(8)" ::: "memory");
    MIDBAR; MFMA_Q(0, 0); ENDBAR;
    // P2: q(0,1) — af reused, 4 reads
    READ_B(bf, cbuf, 1);
    STAGE(cbuf, 0, 0, Abase, k2);
    MIDBAR; MFMA_Q(0, 1); ENDBAR;
    // P3: q(1,1) — bf reused, 8 reads
    READ_A(af, cbuf, 1);
    STAGE(cbuf, 1, 1, Bbase, k2);
    MIDBAR; MFMA_Q(1, 1); ENDBAR;
    // P4: q(1,0) — af reused, 4 reads; tile-boundary vmcnt
    READ_B(bf, cbuf, 0);
    STAGE(cbuf, 0, 1, Abase, k2);
    MIDBAR; MFMA_Q(1, 0);
    __builtin_amdgcn_s_setprio(0);
    asm volatile("s_waitcnt vmcnt(6)" ::: "memory");
    __builtin_amdgcn_s_barrier();
  }

  // --- epilogue: C/D frag layout col=lane&15, row=(lane>>4)*4+reg
  const int row0 = bm * 256, col0 = bn * 256;
  #pragma unroll
  for (int mi = 0; mi < 8; ++mi) {
    const int row = row0 + (mi >> 2) * 128 + wm * 64 + (mi & 3) * 16 + lk * 4;
    #pragma unroll
    for (int ni = 0; ni < 4; ++ni) {
      const int col = col0 + (ni >> 1) * 128 + wn * 32 + (ni & 1) * 16 + lr;
      const float bv = bias[col];
      #pragma unroll
      for (int r = 0; r < 4; ++r) {
        float v = acc[mi][ni][r] + bv;
        if (ACT == 0) v = fmaxf(v, 0.f);
        else          v = v / (1.f + __expf(-v));
        C[(size_t)(row + r) * N + col] = f2b(v);
      }
    }
  }
#undef STAGE
#undef READ_A
#undef READ_B
#undef MFMA_Q
#undef MIDBAR
#undef ENDBAR
}

// ---------------------------------------------------------------------------
// small 128^2 GEMM (te-table only: M=128).
// ---------------------------------------------------------------------------
template<int ACT>
__global__ __launch_bounds__(256) void gemm_bt(
    const ushort* __restrict__ A, const ushort* __restrict__ BT,
    const float* __restrict__ bias, ushort* __restrict__ C,
    int M, int N, int K)
{
  __shared__ ushort As[128 * 64];
  __shared__ ushort Bs[128 * 64];

  const int tid  = threadIdx.x;
  const int lane = tid & 63;
  const int w    = tid >> 6;

  const int gx  = gridDim.x;
  const int nwg = gx * gridDim.y;
  const int wid = blockIdx.y * gx + blockIdx.x;
  const int q   = nwg >> 3;
  const int L   = (wid & 7) * q + (wid >> 3);
  const int bn  = L % gx;
  const int bm  = L / gx;

  const int wm = w >> 1, wn = w & 1;
  const int lr = lane & 15;
  const int lk = lane >> 4;

  const ushort* Abase = A  + (size_t)bm * 128 * K;
  const ushort* Bbase = BT + (size_t)bn * 128 * K;
  const int srow = w * 8 + (lane >> 3);
  const int scol = (lane & 7) * 8;

  f32x4 acc[4][4];
  #pragma unroll
  for (int i = 0; i < 4; i++)
    #pragma unroll
    for (int j = 0; j < 4; j++) acc[i][j] = f32x4{0.f, 0.f, 0.f, 0.f};

  for (int k0 = 0; k0 < K; k0 += 64) {
    #pragma unroll
    for (int i = 0; i < 4; i++) {
      const int r = srow + i * 32;
      __builtin_amdgcn_global_load_lds(
          (gas_ptr)(Abase + (size_t)r * K + k0 + scol),
          (las_ptr)(As + w * 512 + i * 2048), 16, 0, 0);
    }
    #pragma unroll
    for (int i = 0; i < 4; i++) {
      const int r = srow + i * 32;
      __builtin_amdgcn_global_load_lds(
          (gas_ptr)(Bbase + (size_t)r * K + k0 + scol),
          (las_ptr)(Bs + w * 512 + i * 2048), 16, 0, 0);
    }
    __syncthreads();

    #pragma unroll
    for (int kc = 0; kc < 64; kc += 32) {
      s16x8 af[4], bf[4];
      #pragma unroll
      for (int mi = 0; mi < 4; mi++)
        af[mi] = *(const s16x8*)&As[(wm * 64 + mi * 16 + lr) * 64 + kc + lk * 8];
      #pragma unroll
      for (int ni = 0; ni < 4; ni++)
        bf[ni] = *(const s16x8*)&Bs[(wn * 64 + ni * 16 + lr) * 64 + kc + lk * 8];
      #pragma unroll
      for (int mi = 0; mi < 4; mi++)
        #pragma unroll
        for (int ni = 0; ni < 4; ni++)
          acc[mi][ni] = __builtin_amdgcn_mfma_f32_16x16x32_bf16(
              af[mi], bf[ni], acc[mi][ni], 0, 0, 0);
    }
    __syncthreads();
  }

  const int row0 = bm * 128 + wm * 64;
  const int col0 = bn * 128 + wn * 64;
  #pragma unroll
  for (int ni = 0; ni < 4; ni++) {
    const int col = col0 + ni * 16 + lr;
    const float bv = bias[col];
    #pragma unroll
    for (int mi = 0; mi < 4; mi++) {
      const int row = row0 + mi * 16 + lk * 4;
      #pragma unroll
      for (int r = 0; r < 4; r++) {
        float v = acc[mi][ni][r] + bv;
        if (ACT == 0) v = fmaxf(v, 0.f);
        else          v = v / (1.f + __expf(-v));
        C[(size_t)(row + r) * N + col] = f2b(v);
      }
    }
  }
}

// ---------------------------------------------------------------------------
// weight transpose+convert: W[K,N] f32 -> WT[N,Kpad] bf16 (zero-pad k>=K)
// ---------------------------------------------------------------------------
__global__ void trans_conv(const float* __restrict__ W, ushort* __restrict__ WT,
                           int K, int N, int Kpad)
{
  __shared__ float tile[32][33];
  const int n0 = blockIdx.x * 32, k0 = blockIdx.y * 32;
  const int tx = threadIdx.x, ty = threadIdx.y;   // (32,8)
  #pragma unroll
  for (int r = 0; r < 4; r++) {
    const int k = k0 + ty + r * 8;
    tile[ty + r * 8][tx] = (k < K) ? W[(size_t)k * N + n0 + tx] : 0.f;
  }
  __syncthreads();
  #pragma unroll
  for (int r = 0; r < 4; r++) {
    const int n = n0 + ty + r * 8;
    WT[(size_t)n * Kpad + k0 + tx] = f2b(tile[tx][ty + r * 8]);
  }
}

// f32 [R,Cin] -> bf16 [R,Cpad], zero-padded columns
__global__ void conv_pad(const float* __restrict__ in, ushort* __restrict__ out,
                         int R, int Cin, int Cpad)
{
  const int gid = blockIdx.x * 256 + threadIdx.x;
  if (gid >= R * Cpad) return;
  const int r = gid / Cpad, c = gid - r * Cpad;
  out[gid] = (c < Cin) ? f2b(in[(size_t)r * Cin + c]) : (ushort)0;
}

// ---------------------------------------------------------------------------
// LayerNorm over 1024 cols (eps=1e-3), bf16 in/out. One block (256 thr) / row.
// ---------------------------------------------------------------------------
DEV void ln_row(const ushort* __restrict__ in, const float* __restrict__ gamma,
                const float* __restrict__ beta, ushort* __restrict__ outp,
                int tid, float* red)
{
  s16x4 v = *(const s16x4*)&in[tid * 4];
  const float x0 = b2f((ushort)v[0]), x1 = b2f((ushort)v[1]);
  const float x2 = b2f((ushort)v[2]), x3 = b2f((ushort)v[3]);
  float s = x0 + x1 + x2 + x3;
  float qq = x0 * x0 + x1 * x1 + x2 * x2 + x3 * x3;
  #pragma unroll
  for (int o = 32; o > 0; o >>= 1) { s += __shfl_down(s, o); qq += __shfl_down(qq, o); }
  const int wv = tid >> 6, lane = tid & 63;
  __syncthreads();
  if (lane == 0) { red[wv] = s; red[4 + wv] = qq; }
  __syncthreads();
  s  = red[0] + red[1] + red[2] + red[3];
  qq = red[4] + red[5] + red[6] + red[7];
  const float m   = s * (1.f / 1024.f);
  const float var = qq * (1.f / 1024.f) - m * m;
  const float rs  = rsqrtf(var + 1e-3f);
  const int c = tid * 4;
  s16x4 o;
  o[0] = (short)f2b(gamma[c + 0] * ((x0 - m) * rs) + beta[c + 0]);
  o[1] = (short)f2b(gamma[c + 1] * ((x1 - m) * rs) + beta[c + 1]);
  o[2] = (short)f2b(gamma[c + 2] * ((x2 - m) * rs) + beta[c + 2]);
  o[3] = (short)f2b(gamma[c + 3] * ((x3 - m) * rs) + beta[c + 3]);
  *(s16x4*)&outp[c] = o;
}

__global__ void ln_te(const ushort* __restrict__ in, const float* __restrict__ g,
                      const float* __restrict__ b, ushort* __restrict__ out)
{
  __shared__ float red[8];
  ln_row(in + (size_t)blockIdx.x * 1024, g, b,
         out + (size_t)blockIdx.x * 1024, threadIdx.x, red);
}

// gather te row + LN(ge) + LN(ce) -> X[b,3,1024]
__global__ void assembleX(const int* __restrict__ t, const ushort* __restrict__ tetab,
                          const ushort* __restrict__ ge, const ushort* __restrict__ ce,
                          const float* __restrict__ gG, const float* __restrict__ gB,
                          const float* __restrict__ cG, const float* __restrict__ cB,
                          ushort* __restrict__ X)
{
  __shared__ float red[8];
  const int b = blockIdx.x, tid = threadIdx.x;
  const int tt = t[b];
  *(s16x4*)&X[(size_t)b * 3072 + tid * 4] =
      *(const s16x4*)&tetab[(size_t)tt * 1024 + tid * 4];
  ln_row(ge + (size_t)b * 1024, gG, gB, X + (size_t)b * 3072 + 1024, tid, red);
  ln_row(ce + (size_t)b * 1024, cG, cB, X + (size_t)b * 3072 + 2048, tid, red);
}

// ---------------------------------------------------------------------------
// per-sample 3x3 adjacency mix: out[b,i,:] = sum_j A[b,i,j] * x[b,j,:]
// ---------------------------------------------------------------------------
__global__ void mix3(const ushort* __restrict__ x, const float* __restrict__ Am,
                     ushort* __restrict__ out, int d, int lg, int nB)
{
  const int gid = blockIdx.x * 256 + threadIdx.x;
  const int b = gid >> lg;
  if (b >= nB) return;
  const int c8 = (gid & ((1 << lg) - 1)) << 3;
  const ushort* xb = x   + (size_t)b * 3 * d + c8;
  ushort*       ob = out + (size_t)b * 3 * d + c8;
  s16x8 x0 = *(const s16x8*)xb;
  s16x8 x1 = *(const s16x8*)(xb + d);
  s16x8 x2 = *(const s16x8*)(xb + 2 * d);
  float f0[8], f1[8], f2[8];
  #pragma unroll
  for (int e = 0; e < 8; e++) {
    f0[e] = b2f((ushort)x0[e]); f1[e] = b2f((ushort)x1[e]); f2[e] = b2f((ushort)x2[e]);
  }
  const float* Ab = Am + (size_t)b * 9;
  #pragma unroll
  for (int j = 0; j < 3; j++) {
    const float a0 = Ab[j * 3], a1 = Ab[j * 3 + 1], a2 = Ab[j * 3 + 2];
    s16x8 o;
    #pragma unroll
    for (int e = 0; e < 8; e++)
      o[e] = (short)f2b(a0 * f0[e] + a1 * f1[e] + a2 * f2[e]);
    *(s16x8*)(ob + j * d) = o;
  }
}

// ---------------------------------------------------------------------------
// losses (standalone)
// ---------------------------------------------------------------------------
__global__ void zloss_k(const ushort* __restrict__ z1, const ushort* __restrict__ z2,
                        float* __restrict__ out, int n8)
{
  const int gid = blockIdx.x * 256 + threadIdx.x;
  if (gid >= n8) return;
  const size_t i = (size_t)gid * 8;
  s16x8 a = *(const s16x8*)&z1[i];
  s16x8 b = *(const s16x8*)&z2[i];
  f32x4 o0, o1;
  #pragma unroll
  for (int e = 0; e < 4; e++) {
    float d0 = b2f((ushort)a[e]) - b2f((ushort)b[e]);
    float d1 = b2f((ushort)a[e + 4]) - b2f((ushort)b[e + 4]);
    o0[e] = d0 * d0; o1[e] = d1 * d1;
  }
  *(f32x4*)&out[i] = o0; *(f32x4*)&out[i + 4] = o1;
}

template<int ADD>
__global__ void xloss_k(const ushort* __restrict__ X, const ushort* __restrict__ Xh,
                        float* __restrict__ out, int n8)
{
  const int gid = blockIdx.x * 256 + threadIdx.x;
  if (gid >= n8) return;
  const size_t i = (size_t)gid * 8;
  s16x8 a = *(const s16x8*)&X[i];
  s16x8 b = *(const s16x8*)&Xh[i];
  f32x4 o0, o1;
  #pragma unroll
  for (int e = 0; e < 4; e++) {
    float d0 = b2f((ushort)a[e]) - b2f((ushort)b[e]);
    float d1 = b2f((ushort)a[e + 4]) - b2f((ushort)b[e + 4]);
    o0[e] = 0.5f * d0 * d0; o1[e] = 0.5f * d1 * d1;
  }
  if (ADD) {
    f32x4 p0 = *(const f32x4*)&out[i];
    f32x4 p1 = *(const f32x4*)&out[i + 4];
    #pragma unroll
    for (int e = 0; e < 4; e++) { o0[e] += p0[e]; o1[e] += p1[e]; }
  }
  *(f32x4*)&out[i] = o0; *(f32x4*)&out[i + 4] = o1;
}

// ---------------------------------------------------------------------------
extern "C" void kernel_launch(void* const* d_in, const int* in_sizes, int n_in,
                              void* d_out, int out_size, void* d_ws, size_t ws_size,
                              hipStream_t stream)
{
  const int B = 16384, S = 3 * B;
  const int*   t1 = (const int*)d_in[0];
  const float* g1 = (const float*)d_in[1];
  const float* c1 = (const float*)d_in[2];
  const float* A1 = (const float*)d_in[3];
  const int*   t2 = (const int*)d_in[4];
  const float* g2 = (const float*)d_in[5];
  const float* c2 = (const float*)d_in[6];
  const float* A2 = (const float*)d_in[7];
  const float* embed = (const float*)d_in[8];
  const float* Wt = (const float*)d_in[9];  const float* bt = (const float*)d_in[10];
  const float* Wg = (const float*)d_in[11]; const float* bg = (const float*)d_in[12];
  const float* Wc = (const float*)d_in[13]; const float* bc = (const float*)d_in[14];
  const float* lntg = (const float*)d_in[15]; const float* lntb = (const float*)d_in[16];
  const float* lngg = (const float*)d_in[17]; const float* lngb = (const float*)d_in[18];
  const float* lncg = (const float*)d_in[19]; const float* lncb = (const float*)d_in[20];
  const float* eW0 = (const float*)d_in[21]; const float* eb0 = (const float*)d_in[22];
  const float* eW1 = (const float*)d_in[23]; const float* eb1 = (const float*)d_in[24];
  const float* eW2 = (const float*)d_in[25]; const float* eb2 = (const float*)d_in[26];
  const float* dW0 = (const float*)d_in[27]; const float* db0 = (const float*)d_in[28];
  const float* dW1 = (const float*)d_in[29]; const float* db1 = (const float*)d_in[30];
  const float* dW2 = (const float*)d_in[31]; const float* db2 = (const float*)d_in[32];
  float* out = (float*)d_out;
  (void)in_sizes; (void)n_in; (void)out_size; (void)ws_size;

  char* ws = (char*)d_ws; size_t off = 0;
  auto alloc = [&](size_t bytes) -> void* {
    void* p = ws + off; off += (bytes + 255) & ~(size_t)255; return p;
  };
  ushort* WtT  = (ushort*)alloc((size_t)1024 * 1024 * 2);
  ushort* WgT  = (ushort*)alloc((size_t)1024 * 896 * 2);
  ushort* WcT  = (ushort*)alloc((size_t)1024 * 128 * 2);
  ushort* E0T  = (ushort*)alloc((size_t)1024 * 1024 * 2);
  ushort* E1T  = (ushort*)alloc((size_t)512 * 1024 * 2);
  ushort* E2T  = (ushort*)alloc((size_t)256 * 512 * 2);
  ushort* D0T  = (ushort*)alloc((size_t)512 * 256 * 2);
  ushort* D1T  = (ushort*)alloc((size_t)1024 * 512 * 2);
  ushort* D2T  = (ushort*)alloc((size_t)1024 * 1024 * 2);
  ushort* embB = (ushort*)alloc((size_t)128 * 1024 * 2);
  ushort* teraw= (ushort*)alloc((size_t)128 * 1024 * 2);
  ushort* tetab= (ushort*)alloc((size_t)128 * 1024 * 2);
  ushort* gB[2] = {(ushort*)alloc((size_t)B * 896 * 2), (ushort*)alloc((size_t)B * 896 * 2)};
  ushort* cB[2] = {(ushort*)alloc((size_t)B * 128 * 2), (ushort*)alloc((size_t)B * 128 * 2)};
  ushort* zB[2] = {(ushort*)alloc((size_t)S * 256 * 2), (ushort*)alloc((size_t)S * 256 * 2)};
  ushort* Xb = (ushort*)alloc((size_t)S * 1024 * 2);
  ushort* b0 = (ushort*)alloc((size_t)S * 1024 * 2);
  ushort* b1 = (ushort*)alloc((size_t)S * 1024 * 2);

  const dim3 TB(32, 8);
  // weights -> bf16 transposed [N][Kpad]
  trans_conv<<<dim3(32, 32), TB, 0, stream>>>(Wt,  WtT, 1024, 1024, 1024);
  trans_conv<<<dim3(32, 28), TB, 0, stream>>>(Wg,  WgT,  772, 1024,  896);
  trans_conv<<<dim3(32,  4), TB, 0, stream>>>(Wc,  WcT,  100, 1024,  128);
  trans_conv<<<dim3(32, 32), TB, 0, stream>>>(eW0, E0T, 1024, 1024, 1024);
  trans_conv<<<dim3(16, 32), TB, 0, stream>>>(eW1, E1T, 1024,  512, 1024);
  trans_conv<<<dim3( 8, 16), TB, 0, stream>>>(eW2, E2T,  512,  256,  512);
  trans_conv<<<dim3(16,  8), TB, 0, stream>>>(dW0, D0T,  256,  512,  256);
  trans_conv<<<dim3(32, 16), TB, 0, stream>>>(dW1, D1T,  512, 1024,  512);
  trans_conv<<<dim3(32, 32), TB, 0, stream>>>(dW2, D2T, 1024, 1024, 1024);
  // activations -> bf16 (K zero-padded)
  conv_pad<<<512, 256, 0, stream>>>(embed, embB, 128, 1024, 1024);
  conv_pad<<<(B * 896 + 255) / 256, 256, 0, stream>>>(g1, gB[0], B, 772, 896);
  conv_pad<<<(B * 896 + 255) / 256, 256, 0, stream>>>(g2, gB[1], B, 772, 896);
  conv_pad<<<B * 128 / 256, 256, 0, stream>>>(c1, cB[0], B, 100, 128);
  conv_pad<<<B * 128 / 256, 256, 0, stream>>>(c2, cB[1], B, 100, 128);
  // te table: relu(embed@Wt+bt) then LN  (128 tokens only)
  gemm_bt<0><<<dim3(8, 1), 256, 0, stream>>>(embB, WtT, bt, teraw, 128, 1024, 1024);
  ln_te<<<128, 256, 0, stream>>>(teraw, lntg, lntb, tetab);

  const size_t ZLEN = (size_t)S * 256;
  for (int br = 0; br < 2; ++br) {
    const int*   t    = br ? t2 : t1;
    const float* Aadj = br ? A2 : A1;
    // input projections (gemm256: M%256, N%256, K%128 all satisfied)
    gemm256<0><<<dim3(4, B / 256), 512, 0, stream>>>(gB[br], WgT, bg, b0, B, 1024, 896);
    gemm256<0><<<dim3(4, B / 256), 512, 0, stream>>>(cB[br], WcT, bc, b1, B, 1024, 128);
    assembleX<<<B, 256, 0, stream>>>(t, tetab, b0, b1, lngg, lngb, lncg, lncb, Xb);
    // encoder (relu)
    mix3<<<(B << 7) / 256, 256, 0, stream>>>(Xb, Aadj, b0, 1024, 7, B);
    gemm256<0><<<dim3(4, S / 256), 512, 0, stream>>>(b0, E0T, eb0, b1, S, 1024, 1024);
    mix3<<<(B << 7) / 256, 256, 0, stream>>>(b1, Aadj, b0, 1024, 7, B);
    gemm256<0><<<dim3(2, S / 256), 512, 0, stream>>>(b0, E1T, eb1, b1, S, 512, 1024);
    mix3<<<(B << 6) / 256, 256, 0, stream>>>(b1, Aadj, b0, 512, 6, B);
    gemm256<0><<<dim3(1, S / 256), 512, 0, stream>>>(b0, E2T, eb2, zB[br], S, 256, 512);
    // decoder (silu)
    mix3<<<(B << 5) / 256, 256, 0, stream>>>(zB[br], Aadj, b0, 256, 5, B);
    gemm256<1><<<dim3(2, S / 256), 512, 0, stream>>>(b0, D0T, db0, b1, S, 512, 256);
    mix3<<<(B << 6) / 256, 256, 0, stream>>>(b1, Aadj, b0, 512, 6, B);
    gemm256<1><<<dim3(4, S / 256), 512, 0, stream>>>(b0, D1T, db1, b1, S, 1024, 512);
    mix3<<<(B << 7) / 256, 256, 0, stream>>>(b1, Aadj, b0, 1024, 7, B);
    gemm256<1><<<dim3(4, S / 256), 512, 0, stream>>>(b0, D2T, db2, b1, S, 1024, 1024);
    // X reconstruction loss (br0 writes, br1 accumulates)
    if (br == 0)
      xloss_k<0><<<S * 1024 / 8 / 256, 256, 0, stream>>>(Xb, b1, out + ZLEN, S * 1024 / 8);
    else
      xloss_k<1><<<S * 1024 / 8 / 256, 256, 0, stream>>>(Xb, b1, out + ZLEN, S * 1024 / 8);
  }
  zloss_k<<<S * 256 / 8 / 256, 256, 0, stream>>>(zB[0], zB[1], out, S * 256 / 8);
}